// Round 15
// baseline (198.595 us; speedup 1.0000x reference)
//
#include <hip/hip_runtime.h>
#include <hip/hip_fp16.h>
#include <cstdint>

// Problem shape
#define B_   256
#define CIN  3
#define HW_  64
#define COUT 64
#define FIN  65536   // 64*32*32
#define FOUT 256

// Workspace layout (float indices)
#define ACC_F    0        // 65536: split-K accumulator (FALLBACK path only)
#define SC_F     65536    // 16: [1] = max_h bits (atomicMax; zeroed by k_stats)
#define XPART_F  65552    // 512: per-block partial absmax of x (plain writes)
#define WPART_F  66064    // 1024: per-(row,quarter) partial absmax of dense_w
#define CSF_F    67088    // 64: conv per-channel weight scale
#define CWINT_F  67152    // 1728: conv w_int (float-valued, s_load path in k_conv)
#define H16_BYTE (512*1024)                          // f16 h buffer, 33.5 MB
#define WQ_BYTE  (H16_BYTE + 256ll*FIN*2)            // (unused now; layout kept)
#define REP_BYTE (WQ_BYTE + 256ll*FIN)               // 64 x 256KB f32 replicas, 16.8 MB
#define WS_NEED  (REP_BYTE + 64ll*B_*FOUT*4)         // ~67.6 MB (proven present, r14)

typedef _Float16 half8  __attribute__((ext_vector_type(8)));
typedef _Float16 half4v __attribute__((ext_vector_type(4)));
typedef float    floatx4 __attribute__((ext_vector_type(4)));
typedef unsigned short u16;
typedef unsigned int uint_;

__device__ inline float blockMax(float v) {
    #pragma unroll
    for (int off = 32; off; off >>= 1) v = fmaxf(v, __shfl_down(v, off));
    __shared__ float sm[8];
    const int lane = threadIdx.x & 63, w = threadIdx.x >> 6;
    if (lane == 0) sm[w] = v;
    __syncthreads();
    float m = sm[0];
    const int nw = blockDim.x >> 6;
    for (int i = 1; i < nw; i++) m = fmaxf(m, sm[i]);
    return m;
}

// ---- kernel 1: input stats + conv weight quant (+ accb zero, fallback only) ----
__global__ __launch_bounds__(256) void k_stats(const float* __restrict__ x,
                                               const float* __restrict__ dw,
                                               const float* __restrict__ cw,
                                               float* __restrict__ ws) {
    const int b = blockIdx.x;
    const int t = threadIdx.x;
    if (b < 512) {
        const float4* x4 = (const float4*)x;
        float m = 0.f;
        for (int i = b * 256 + t; i < (B_ * CIN * HW_ * HW_) / 4; i += 512 * 256) {
            float4 v = x4[i];
            m = fmaxf(m, fmaxf(fmaxf(fabsf(v.x), fabsf(v.y)), fmaxf(fabsf(v.z), fabsf(v.w))));
        }
        float bm = blockMax(m);
        if (t == 0) ws[XPART_F + b] = bm;
    } else if (b < 1536) {
        const int b2 = b - 512;
        const int row = b2 >> 2, q = b2 & 3;
        const float4* r = (const float4*)(dw + (size_t)row * FIN) + q * 4096;
        float m = 0.f;
        for (int i = t; i < 4096; i += 256) {
            float4 v = r[i];
            m = fmaxf(m, fmaxf(fmaxf(fabsf(v.x), fabsf(v.y)), fmaxf(fabsf(v.z), fabsf(v.w))));
        }
        float bm = blockMax(m);
        if (t == 0) ws[WPART_F + b2] = bm;
    } else if (b == 1536) {
        if (t == 64) ((unsigned*)ws)[SC_F + 1] = 0u;   // zero max_h slot for k_conv's atomicMax
        if (t < 64) {
            const int o = t;
            float wv[27];
            float m = 0.f;
            #pragma unroll
            for (int i = 0; i < 27; i++) { wv[i] = cw[o * 27 + i]; m = fmaxf(m, fabsf(wv[i])); }
            const float sf = fmaxf(m, 1e-8f) / 127.0f;
            #pragma unroll
            for (int i = 0; i < 27; i++)
                ws[CWINT_F + o * 27 + i] = fminf(127.f, fmaxf(-127.f, rintf(wv[i] / sf)));
            ws[CSF_F + o] = sf;
        }
    } else {
        // fallback path only: zero the atomic accumulator
        ws[ACC_F + (b - 1537) * 256 + t] = 0.f;
    }
}

// ---- kernel 2: PURE conv 3x3 s2 p1 (quant epilogue REMOVED -- r15: the
//      dw read+wq write moved into gemm's measured latency slack) ----
__global__ __launch_bounds__(256) void k_conv(const float* __restrict__ x,
                                              const float* __restrict__ cb,
                                              const float* __restrict__ ws,
                                              u16* __restrict__ h16,
                                              unsigned* __restrict__ maxh) {
    const int t = threadIdx.x;

    __shared__ float s_bsf[64], s_bint[64];
    __shared__ float xt[27 * 68];   // staged+requantized input, halo cols

    float pm = fmaxf(ws[XPART_F + t], ws[XPART_F + 256 + t]);
    pm = blockMax(pm);
    const float p_sf = fmaxf(pm, 1e-8f) / 32767.0f;
    const float inv_p = 1.0f / p_sf;
    if (t < 64) {
        const float bsf = p_sf * ws[CSF_F + t];
        s_bsf[t]  = bsf;
        s_bint[t] = rintf(cb[t] / bsf);
    }

    const int b   = blockIdx.x >> 3;
    const int oyt = (blockIdx.x & 7) * 4;
    const float* xb = x + (size_t)b * (CIN * HW_ * HW_);

    for (int i = t; i < 432; i += 256) {
        const int lrow = i >> 4, c4 = i & 15;
        const int ci = lrow / 9, lr = lrow - ci * 9;
        const int iy = 2 * oyt - 1 + lr;
        float4 v = make_float4(0.f, 0.f, 0.f, 0.f);
        if ((unsigned)iy < 64u) v = *(const float4*)(xb + (ci * HW_ + iy) * HW_ + c4 * 4);
        float* d = &xt[lrow * 68 + 1 + c4 * 4];
        d[0] = rintf(v.x * inv_p);   // |v|*inv_p <= 32767 by construction
        d[1] = rintf(v.y * inv_p);
        d[2] = rintf(v.z * inv_p);
        d[3] = rintf(v.w * inv_p);
    }
    if (t < 27) xt[t * 68] = 0.f;
    else if (t < 54) xt[(t - 27) * 68 + 65] = 0.f;
    __syncthreads();

    const int ox = t & 31;
    const int ch = __builtin_amdgcn_readfirstlane((t >> 6) & 1);
    const int dy = ((t >> 7) << 1) + ((t >> 5) & 1);
    const int oy = oyt + dy;

    // xs straight from xt, pinned to VGPRs
    float xs[27];
    #pragma unroll
    for (int ci = 0; ci < 3; ci++)
        #pragma unroll
        for (int ky = 0; ky < 3; ky++) {
            const float* rowp = &xt[(ci * 9 + 2 * dy + ky) * 68 + 2 * ox];
            float a0 = rowp[0], a1 = rowp[1], a2 = rowp[2];
            asm volatile("" : "+v"(a0), "+v"(a1), "+v"(a2));
            xs[ci * 9 + ky * 3 + 0] = a0;
            xs[ci * 9 + ky * 3 + 1] = a1;
            xs[ci * 9 + ky * 3 + 2] = a2;
        }

    const float* wr = ws + CWINT_F + ch * (32 * 27);  // uniform + const -> s_load
    float mx = 0.f;
    u16* outp = h16 + (size_t)b * FIN + (size_t)ch * 32 * 1024 + oy * 32 + ox;

#define EMIT(cc, aa) { const int co_ = ch * 32 + (cc); \
    float h_ = ((aa) + s_bint[co_]) * s_bsf[co_]; \
    h_ = fmaxf(h_, 0.f); mx = fmaxf(mx, h_); \
    outp[(size_t)(cc) * 1024] = __half_as_ushort(__float2half(h_)); }

    // two NAMED weight buffers: next channel's s_loads overlap current fmas
    float wA[27], wB[27];
    #pragma unroll
    for (int k = 0; k < 27; k++) wA[k] = wr[k];
    #pragma unroll
    for (int c = 0; c < 32; c += 2) {
        #pragma unroll
        for (int k = 0; k < 27; k++) wB[k] = wr[(c + 1) * 27 + k];
        float a = 0.f;
        #pragma unroll
        for (int k = 0; k < 27; k++) a = fmaf(xs[k], wA[k], a);
        EMIT(c, a);
        if (c + 2 < 32) {
            #pragma unroll
            for (int k = 0; k < 27; k++) wA[k] = wr[(c + 2) * 27 + k];
        }
        float a2 = 0.f;
        #pragma unroll
        for (int k = 0; k < 27; k++) a2 = fmaf(xs[k], wB[k], a2);
        EMIT(c + 1, a2);
    }
#undef EMIT
    float bm = blockMax(mx);
    if (t == 0) atomicMax(maxh, __float_as_uint(bm));
}

// ---- gemm main-loop body (f32 B with on-the-fly requant via invB; 2-deep
//      ping-pong -- r13 proved 3-deep === 2-deep, and f32-B triples the B
//      register sets so 2-deep keeps VGPR under the spill line) ----
#define GEMM_BODY(EPILOGUE) \
    __shared__ __align__(16) _Float16 As[128][72]; \
    __shared__ __align__(16) _Float16 Bs[128][72]; \
    __shared__ float invB[128]; \
    const int tid = threadIdx.x; \
    const int tm  = (blockIdx.x >> 1) * 128; \
    const int tn  = (blockIdx.x & 1) * 128; \
    const int k0  = blockIdx.y * 1024; \
    const float max_h  = __uint_as_float(((const unsigned*)ws)[SC_F + 1]); \
    const float p2     = fmaxf(max_h, 1e-8f) / 1023.0f; \
    const float inv_p2 = 1.0f / p2; \
    if (tid < 128) { \
        const float* wp = ws + WPART_F + (size_t)(tn + tid) * 4; \
        const float am = fmaxf(fmaxf(wp[0], wp[1]), fmaxf(wp[2], wp[3])); \
        invB[tid] = 127.0f / fmaxf(am, 1e-8f); \
    } \
    __syncthreads(); \
    floatx4 acc[4][4]; \
    const floatx4 zz = {0.f, 0.f, 0.f, 0.f}; \
    _Pragma("unroll") \
    for (int i = 0; i < 4; i++) _Pragma("unroll") \
        for (int j = 0; j < 4; j++) acc[i][j] = zz; \
    const int wv = tid >> 6, lane = tid & 63; \
    const int wm = (wv >> 1) * 64, wn = (wv & 1) * 64; \
    const int lm = lane & 15, quad = lane >> 4; \
    const int arow = tid >> 3, acol = tid & 7; \
    const int brow = tid >> 4, bcol = tid & 15; \
    const u16* abase = h16 + (size_t)(tm + arow) * FIN + k0 + acol * 8; \
    const float* bbase = dw + (size_t)(tn + brow) * FIN + k0 + bcol * 4; \
    half8  a0[4], a1[4]; \
    float4 b0[8], b1[8]; \
    LOADA(a0, 0); LOADB(b0, 0); \
    LOADA(a1, 1); LOADB(b1, 1); \
    for (int it = 0; it < 8; ++it) { \
        PHASE(a0, b0, 2 * it); \
        PHASE(a1, b1, 2 * it + 1); \
    } \
    EPILOGUE

#define LOADA(dst, kk) { _Pragma("unroll") \
    for (int r = 0; r < 4; r++) \
        dst[r] = *(const half8*)(abase + (size_t)r * 32 * FIN + (kk) * 64); }
#define LOADB(dst, kk) { _Pragma("unroll") \
    for (int r = 0; r < 8; r++) \
        dst[r] = *(const float4*)(bbase + (size_t)r * 16 * FIN + (kk) * 64); }
#define STAGEA(src) { _Pragma("unroll") \
    for (int r = 0; r < 4; r++) { half8 qv; _Pragma("unroll") \
        for (int j = 0; j < 8; j++) { float f_ = (float)src[r][j]; \
            qv[j] = (_Float16)fminf(1023.f, rintf(f_ * inv_p2)); } \
        *(half8*)&As[arow + r * 32][acol * 8] = qv; } }
#define STAGEB(src) { _Pragma("unroll") \
    for (int r = 0; r < 8; r++) { \
        const float is_ = invB[brow + r * 16]; \
        float4 v_ = src[r]; \
        half4v qv; \
        qv[0] = (_Float16)rintf(v_.x * is_);   /* |v|*is <= 127 by construction */ \
        qv[1] = (_Float16)rintf(v_.y * is_); \
        qv[2] = (_Float16)rintf(v_.z * is_); \
        qv[3] = (_Float16)rintf(v_.w * is_); \
        *(half4v*)&Bs[brow + r * 16][bcol * 4] = qv; } }
#define BARRIER() do { asm volatile("s_waitcnt lgkmcnt(0)" ::: "memory"); \
    __builtin_amdgcn_s_barrier(); } while (0)
#define MFMA_PHASE() { _Pragma("unroll") \
    for (int ks = 0; ks < 2; ks++) { half8 af[4], bf[4]; _Pragma("unroll") \
        for (int mi = 0; mi < 4; mi++) \
            af[mi] = *(const half8*)&As[wm + mi * 16 + lm][ks * 32 + quad * 8]; \
        _Pragma("unroll") \
        for (int ni = 0; ni < 4; ni++) \
            bf[ni] = *(const half8*)&Bs[wn + ni * 16 + lm][ks * 32 + quad * 8]; \
        _Pragma("unroll") \
        for (int mi = 0; mi < 4; mi++) _Pragma("unroll") \
            for (int ni = 0; ni < 4; ni++) \
                acc[mi][ni] = __builtin_amdgcn_mfma_f32_16x16x32_f16(af[mi], bf[ni], acc[mi][ni], 0, 0, 0); } }
#define PHASE(As_, Bs_, kk) { \
    STAGEA(As_); STAGEB(Bs_); \
    if ((kk) + 2 < 16) { LOADA(As_, (kk) + 2); LOADB(Bs_, (kk) + 2); } \
    BARRIER(); \
    MFMA_PHASE(); \
    BARRIER(); }

// ---- kernel 3a: GEMM + per-slice REPLICA plain stores ----
__global__ __launch_bounds__(256) void k_gemm_rep(const u16* __restrict__ h16,
                                                  const float* __restrict__ dw,
                                                  const float* __restrict__ ws,
                                                  float* __restrict__ rep) {
    GEMM_BODY({
        float* rp = rep + (size_t)blockIdx.y * (B_ * FOUT);
        _Pragma("unroll")
        for (int mi = 0; mi < 4; mi++) _Pragma("unroll")
            for (int ni = 0; ni < 4; ni++) _Pragma("unroll")
                for (int r = 0; r < 4; r++) {
                    const int row = tm + wm + mi * 16 + quad * 4 + r;
                    const int col = tn + wn + ni * 16 + lm;
                    rp[row * FOUT + col] = acc[mi][ni][r];
                }
    })
}

// ---- kernel 3b: GEMM + atomic accumulate (fallback if ws too small) ----
__global__ __launch_bounds__(256) void k_gemm_atm(const u16* __restrict__ h16,
                                                  const float* __restrict__ dw,
                                                  const float* __restrict__ ws,
                                                  float* __restrict__ accb) {
    GEMM_BODY({
        _Pragma("unroll")
        for (int mi = 0; mi < 4; mi++) _Pragma("unroll")
            for (int ni = 0; ni < 4; ni++) _Pragma("unroll")
                for (int r = 0; r < 4; r++) {
                    const int row = tm + wm + mi * 16 + quad * 4 + r;
                    const int col = tn + wn + ni * 16 + lm;
                    atomicAdd(accb + row * FOUT + col, acc[mi][ni][r]);
                }
    })
}
#undef LOADA
#undef LOADB
#undef STAGEA
#undef STAGEB
#undef BARRIER
#undef MFMA_PHASE
#undef PHASE
#undef GEMM_BODY

// ---- kernel 4a: reduce 64 replicas + bias + relu ----
__global__ void k_epi_rep(const float* __restrict__ rep, const float* __restrict__ db,
                          const float* __restrict__ ws, float* __restrict__ out) {
    const int idx = blockIdx.x * 256 + threadIdx.x;
    float s0 = 0.f, s1 = 0.f, s2 = 0.f, s3 = 0.f;
    #pragma unroll
    for (int r = 0; r < 64; r += 4) {
        s0 += rep[(size_t)(r + 0) * (B_ * FOUT) + idx];
        s1 += rep[(size_t)(r + 1) * (B_ * FOUT) + idx];
        s2 += rep[(size_t)(r + 2) * (B_ * FOUT) + idx];
        s3 += rep[(size_t)(r + 3) * (B_ * FOUT) + idx];
    }
    const float sum = (s0 + s1) + (s2 + s3);
    const int n = idx & 255;
    const float max_h = __uint_as_float(((const unsigned*)ws)[SC_F + 1]);
    const float p2 = fmaxf(max_h, 1e-8f) / 1023.0f;
    const float* wp = ws + WPART_F + (size_t)n * 4;
    const float am = fmaxf(fmaxf(fmaxf(wp[0], wp[1]), fmaxf(wp[2], wp[3])), 1e-8f);
    const float bsf = p2 * (am / 127.0f);
    const float bint = rintf(db[n] / bsf);
    out[idx] = fmaxf(0.f, (sum + bint) * bsf);
}

// ---- kernel 4b: fallback epilogue over atomic accb ----
__global__ void k_epi_atm(const float* __restrict__ accb, const float* __restrict__ db,
                          const float* __restrict__ ws, float* __restrict__ out) {
    const int idx = blockIdx.x * 256 + threadIdx.x;
    const int n = idx & 255;
    const float max_h = __uint_as_float(((const unsigned*)ws)[SC_F + 1]);
    const float p2 = fmaxf(max_h, 1e-8f) / 1023.0f;
    const float* wp = ws + WPART_F + (size_t)n * 4;
    const float am = fmaxf(fmaxf(fmaxf(wp[0], wp[1]), fmaxf(wp[2], wp[3])), 1e-8f);
    const float bsf = p2 * (am / 127.0f);
    const float bint = rintf(db[n] / bsf);
    out[idx] = fmaxf(0.f, (accb[idx] + bint) * bsf);
}

extern "C" void kernel_launch(void* const* d_in, const int* in_sizes, int n_in,
                              void* d_out, int out_size, void* d_ws, size_t ws_size,
                              hipStream_t stream) {
    (void)in_sizes; (void)n_in; (void)out_size;
    const float* x  = (const float*)d_in[0];
    const float* cw = (const float*)d_in[1];
    const float* cb = (const float*)d_in[2];
    const float* dw = (const float*)d_in[3];
    const float* db = (const float*)d_in[4];
    float* out = (float*)d_out;
    float* ws  = (float*)d_ws;
    u16* h16   = (u16*)((char*)d_ws + H16_BYTE);
    float* rep  = (float*)((char*)d_ws + REP_BYTE);
    float* accb = ws + ACC_F;
    unsigned* maxh = (unsigned*)ws + SC_F + 1;

    const bool use_rep = (ws_size >= (size_t)WS_NEED);

    // 4 enqueues: stats -> conv (pure) -> gemm(f32-B requant) -> epilogue
    k_stats<<<use_rep ? 1537 : 1793, 256, 0, stream>>>(x, dw, cw, ws);
    k_conv<<<2048, 256, 0, stream>>>(x, cb, ws, h16, maxh);
    if (use_rep) {
        k_gemm_rep<<<dim3(4, 64), 256, 0, stream>>>(h16, dw, ws, rep);
        k_epi_rep<<<256, 256, 0, stream>>>(rep, db, ws, out);
    } else {
        k_gemm_atm<<<dim3(4, 64), 256, 0, stream>>>(h16, dw, ws, accb);
        k_epi_atm<<<256, 256, 0, stream>>>(accb, db, ws, out);
    }
}

// Round 16
// 187.446 us; speedup vs baseline: 1.0595x; 1.0595x over previous
//
#include <hip/hip_runtime.h>
#include <hip/hip_fp16.h>
#include <cstdint>

// Problem shape
#define B_   256
#define CIN  3
#define HW_  64
#define COUT 64
#define FIN  65536   // 64*32*32
#define FOUT 256

// Workspace layout (float indices)
#define ACC_F    0        // 65536: split-K accumulator (FALLBACK path only)
#define SC_F     65536    // 16: [1] = max_h bits (atomicMax; zeroed by k_stats)
#define XPART_F  65552    // 512: per-block partial absmax of x (plain writes)
#define WPART_F  66064    // 1024: per-(row,quarter) partial absmax of dense_w
#define CSF_F    67088    // 64: conv per-channel weight scale
#define CWINT_F  67152    // 1728: conv w_int (float-valued, s_load path in k_conv)
#define H16_BYTE (512*1024)                          // f16 h buffer, 33.5 MB
#define WQ_BYTE  (H16_BYTE + 256ll*FIN*2)            // int8 dense_w, 16.7 MB
#define REP_BYTE (WQ_BYTE + 256ll*FIN)               // f32 replicas start here
#define WS_N64   (REP_BYTE + 64ll*B_*FOUT*4)         // ~67.6 MB (proven, r14)
#define WS_N128  (REP_BYTE + 128ll*B_*FOUT*4)        // ~84.4 MB

typedef _Float16 half8  __attribute__((ext_vector_type(8)));
typedef float    floatx4 __attribute__((ext_vector_type(4)));
typedef unsigned short u16;
typedef unsigned int uint_;

__device__ inline float blockMax(float v) {
    #pragma unroll
    for (int off = 32; off; off >>= 1) v = fmaxf(v, __shfl_down(v, off));
    __shared__ float sm[8];
    const int lane = threadIdx.x & 63, w = threadIdx.x >> 6;
    if (lane == 0) sm[w] = v;
    __syncthreads();
    float m = sm[0];
    const int nw = blockDim.x >> 6;
    for (int i = 1; i < nw; i++) m = fmaxf(m, sm[i]);
    return m;
}

// ---- kernel 1: input stats + conv weight quant (r14-identical) ----
__global__ __launch_bounds__(256) void k_stats(const float* __restrict__ x,
                                               const float* __restrict__ dw,
                                               const float* __restrict__ cw,
                                               float* __restrict__ ws) {
    const int b = blockIdx.x;
    const int t = threadIdx.x;
    if (b < 512) {
        const float4* x4 = (const float4*)x;
        float m = 0.f;
        for (int i = b * 256 + t; i < (B_ * CIN * HW_ * HW_) / 4; i += 512 * 256) {
            float4 v = x4[i];
            m = fmaxf(m, fmaxf(fmaxf(fabsf(v.x), fabsf(v.y)), fmaxf(fabsf(v.z), fabsf(v.w))));
        }
        float bm = blockMax(m);
        if (t == 0) ws[XPART_F + b] = bm;
    } else if (b < 1536) {
        const int b2 = b - 512;
        const int row = b2 >> 2, q = b2 & 3;
        const float4* r = (const float4*)(dw + (size_t)row * FIN) + q * 4096;
        float m = 0.f;
        for (int i = t; i < 4096; i += 256) {
            float4 v = r[i];
            m = fmaxf(m, fmaxf(fmaxf(fabsf(v.x), fabsf(v.y)), fmaxf(fabsf(v.z), fabsf(v.w))));
        }
        float bm = blockMax(m);
        if (t == 0) ws[WPART_F + b2] = bm;
    } else if (b == 1536) {
        if (t == 64) ((unsigned*)ws)[SC_F + 1] = 0u;   // zero max_h slot for k_conv's atomicMax
        if (t < 64) {
            const int o = t;
            float wv[27];
            float m = 0.f;
            #pragma unroll
            for (int i = 0; i < 27; i++) { wv[i] = cw[o * 27 + i]; m = fmaxf(m, fabsf(wv[i])); }
            const float sf = fmaxf(m, 1e-8f) / 127.0f;
            #pragma unroll
            for (int i = 0; i < 27; i++)
                ws[CWINT_F + o * 27 + i] = fminf(127.f, fmaxf(-127.f, rintf(wv[i] / sf)));
            ws[CSF_F + o] = sf;
        }
    } else {
        // fallback path only: zero the atomic accumulator
        ws[ACC_F + (b - 1537) * 256 + t] = 0.f;
    }
}

// ---- kernel 2: conv 3x3 s2 p1 + fused dense_w quant epilogue ----
// BYTE-IDENTICAL to r14 (best, 51.5us). r15 lesson: even REMOVING work from
// this kernel reshuffles codegen and costs 25% (65.5us). Do not touch.
__global__ __launch_bounds__(256) void k_conv(const float* __restrict__ x,
                                              const float* __restrict__ dw,
                                              const float* __restrict__ cb,
                                              const float* __restrict__ ws,
                                              u16* __restrict__ h16,
                                              signed char* __restrict__ wq,
                                              unsigned* __restrict__ maxh) {
    const int t = threadIdx.x;

    __shared__ float s_bsf[64], s_bint[64];
    __shared__ float xt[27 * 68];   // staged+requantized input, halo cols

    float pm = fmaxf(ws[XPART_F + t], ws[XPART_F + 256 + t]);
    pm = blockMax(pm);
    const float p_sf = fmaxf(pm, 1e-8f) / 32767.0f;
    const float inv_p = 1.0f / p_sf;
    if (t < 64) {
        const float bsf = p_sf * ws[CSF_F + t];
        s_bsf[t]  = bsf;
        s_bint[t] = rintf(cb[t] / bsf);
    }

    const int b   = blockIdx.x >> 3;
    const int oyt = (blockIdx.x & 7) * 4;
    const float* xb = x + (size_t)b * (CIN * HW_ * HW_);

    for (int i = t; i < 432; i += 256) {
        const int lrow = i >> 4, c4 = i & 15;
        const int ci = lrow / 9, lr = lrow - ci * 9;
        const int iy = 2 * oyt - 1 + lr;
        float4 v = make_float4(0.f, 0.f, 0.f, 0.f);
        if ((unsigned)iy < 64u) v = *(const float4*)(xb + (ci * HW_ + iy) * HW_ + c4 * 4);
        float* d = &xt[lrow * 68 + 1 + c4 * 4];
        d[0] = rintf(v.x * inv_p);   // |v|*inv_p <= 32767 by construction
        d[1] = rintf(v.y * inv_p);
        d[2] = rintf(v.z * inv_p);
        d[3] = rintf(v.w * inv_p);
    }
    if (t < 27) xt[t * 68] = 0.f;
    else if (t < 54) xt[(t - 27) * 68 + 65] = 0.f;
    __syncthreads();

    const int ox = t & 31;
    const int ch = __builtin_amdgcn_readfirstlane((t >> 6) & 1);
    const int dy = ((t >> 7) << 1) + ((t >> 5) & 1);
    const int oy = oyt + dy;

    // xs straight from xt, pinned to VGPRs
    float xs[27];
    #pragma unroll
    for (int ci = 0; ci < 3; ci++)
        #pragma unroll
        for (int ky = 0; ky < 3; ky++) {
            const float* rowp = &xt[(ci * 9 + 2 * dy + ky) * 68 + 2 * ox];
            float a0 = rowp[0], a1 = rowp[1], a2 = rowp[2];
            asm volatile("" : "+v"(a0), "+v"(a1), "+v"(a2));
            xs[ci * 9 + ky * 3 + 0] = a0;
            xs[ci * 9 + ky * 3 + 1] = a1;
            xs[ci * 9 + ky * 3 + 2] = a2;
        }

    const float* wr = ws + CWINT_F + ch * (32 * 27);  // uniform + const -> s_load
    float mx = 0.f;
    u16* outp = h16 + (size_t)b * FIN + (size_t)ch * 32 * 1024 + oy * 32 + ox;

#define EMIT(cc, aa) { const int co_ = ch * 32 + (cc); \
    float h_ = ((aa) + s_bint[co_]) * s_bsf[co_]; \
    h_ = fmaxf(h_, 0.f); mx = fmaxf(mx, h_); \
    outp[(size_t)(cc) * 1024] = __half_as_ushort(__float2half(h_)); }

    // two NAMED weight buffers: next channel's s_loads overlap current fmas
    float wA[27], wB[27];
    #pragma unroll
    for (int k = 0; k < 27; k++) wA[k] = wr[k];
    #pragma unroll
    for (int c = 0; c < 32; c += 2) {
        #pragma unroll
        for (int k = 0; k < 27; k++) wB[k] = wr[(c + 1) * 27 + k];
        float a = 0.f;
        #pragma unroll
        for (int k = 0; k < 27; k++) a = fmaf(xs[k], wA[k], a);
        EMIT(c, a);
        if (c + 2 < 32) {
            #pragma unroll
            for (int k = 0; k < 27; k++) wA[k] = wr[(c + 2) * 27 + k];
        }
        float a2 = 0.f;
        #pragma unroll
        for (int k = 0; k < 27; k++) a2 = fmaf(xs[k], wB[k], a2);
        EMIT(c + 1, a2);
    }
#undef EMIT
    float bm = blockMax(mx);
    if (t == 0) atomicMax(maxh, __float_as_uint(bm));

    // ---- fused dense_w quant epilogue: this block's 1/2048 share (8KB wq) ----
    {
        const int row = blockIdx.x >> 3;        // 0..255
        const int e8  = blockIdx.x & 7;         // eighth of the row
        const float* wp = ws + WPART_F + row * 4;
        const float am = fmaxf(fmaxf(wp[0], wp[1]), fmaxf(wp[2], wp[3]));
        const float inv = 127.0f / fmaxf(am, 1e-8f);
        const float4* r4 = (const float4*)(dw + (size_t)row * FIN) + e8 * 2048;
        uint_* wrow = (uint_*)(wq + (size_t)row * FIN) + e8 * 2048;
        for (int i = t; i < 2048; i += 256) {
            float4 v = r4[i];
            int q0 = __float2int_rn(v.x * inv);   // |v|*inv <= 127 by construction
            int q1 = __float2int_rn(v.y * inv);
            int q2 = __float2int_rn(v.z * inv);
            int q3 = __float2int_rn(v.w * inv);
            wrow[i] = (uint_)(q0 & 255) | ((uint_)(q1 & 255) << 8) |
                      ((uint_)(q2 & 255) << 16) | ((uint_)(q3 & 255) << 24);
        }
    }
}

// int8x8 -> half8 (values are small ints, exact in f16)
__device__ __forceinline__ half8 cvt_b8(uint_ lo, uint_ hi) {
    half8 h;
    h[0] = (_Float16)(float)(int)(signed char)(lo);
    h[1] = (_Float16)(float)(int)(signed char)(lo >> 8);
    h[2] = (_Float16)(float)(int)(signed char)(lo >> 16);
    h[3] = (_Float16)(float)(int)(signed char)(lo >> 24);
    h[4] = (_Float16)(float)(int)(signed char)(hi);
    h[5] = (_Float16)(float)(int)(signed char)(hi >> 8);
    h[6] = (_Float16)(float)(int)(signed char)(hi >> 16);
    h[7] = (_Float16)(float)(int)(signed char)(hi >> 24);
    return h;
}

// ---- gemm main-loop body, templated on NS (K-slice count) ----
// NS=128: 512 blocks = 2 blocks/CU -- now that replicas removed the atomic
// penalty (the r1/r5 split-K ladder measured ATOMIC cost), extra slices buy
// cross-block stall-filling for free. 2-deep ping-pong (r13: 3-deep === 2-deep).
#define GEMM_BODY(EPILOGUE) \
    constexpr int KS = FIN / NS;      /* K per slice: 512 or 1024 */ \
    constexpr int PH = KS / 64;       /* phases: 8 or 16 */ \
    __shared__ __align__(16) _Float16 As[128][72]; \
    __shared__ __align__(16) _Float16 Bs[128][72]; \
    const int tid = threadIdx.x; \
    const int tm  = (blockIdx.x >> 1) * 128; \
    const int tn  = (blockIdx.x & 1) * 128; \
    const int k0  = blockIdx.y * KS; \
    const float max_h  = __uint_as_float(((const unsigned*)ws)[SC_F + 1]); \
    const float p2     = fmaxf(max_h, 1e-8f) / 1023.0f; \
    const float inv_p2 = 1.0f / p2; \
    floatx4 acc[4][4]; \
    const floatx4 zz = {0.f, 0.f, 0.f, 0.f}; \
    _Pragma("unroll") \
    for (int i = 0; i < 4; i++) _Pragma("unroll") \
        for (int j = 0; j < 4; j++) acc[i][j] = zz; \
    const int wv = tid >> 6, lane = tid & 63; \
    const int wm = (wv >> 1) * 64, wn = (wv & 1) * 64; \
    const int lm = lane & 15, quad = lane >> 4; \
    const int arow = tid >> 3, acol = tid & 7; \
    const int brow = tid >> 1, bq   = (tid & 1) * 32; \
    const u16* abase = h16 + (size_t)(tm + arow) * FIN + k0 + acol * 8; \
    const signed char* bbase = wq + (size_t)(tn + brow) * FIN + k0 + bq; \
    half8 a0[4], a1[4]; \
    uint4 b0[2], b1[2]; \
    LOADA(a0, 0); LOADB(b0, 0); \
    LOADA(a1, 1); LOADB(b1, 1); \
    for (int it = 0; it < PH / 2; ++it) { \
        PHASE(a0, b0, 2 * it); \
        PHASE(a1, b1, 2 * it + 1); \
    } \
    EPILOGUE

#define LOADA(dst, kk) { _Pragma("unroll") \
    for (int r = 0; r < 4; r++) \
        dst[r] = *(const half8*)(abase + (size_t)r * 32 * FIN + (kk) * 64); }
#define LOADB(dst, kk) { const uint4* p_ = (const uint4*)(bbase + (kk) * 64); \
    dst[0] = p_[0]; dst[1] = p_[1]; }
#define STAGEA(src) { _Pragma("unroll") \
    for (int r = 0; r < 4; r++) { half8 qv; _Pragma("unroll") \
        for (int j = 0; j < 8; j++) { float f_ = (float)src[r][j]; \
            qv[j] = (_Float16)fminf(1023.f, rintf(f_ * inv_p2)); } \
        *(half8*)&As[arow + r * 32][acol * 8] = qv; } }
#define STAGEB(src) { _Pragma("unroll") \
    for (int u = 0; u < 2; u++) { uint4 wd_ = src[u]; \
        *(half8*)&Bs[brow][bq + u * 16 + 0] = cvt_b8(wd_.x, wd_.y); \
        *(half8*)&Bs[brow][bq + u * 16 + 8] = cvt_b8(wd_.z, wd_.w); } }
#define BARRIER() do { asm volatile("s_waitcnt lgkmcnt(0)" ::: "memory"); \
    __builtin_amdgcn_s_barrier(); } while (0)
#define MFMA_PHASE() { _Pragma("unroll") \
    for (int ks = 0; ks < 2; ks++) { half8 af[4], bf[4]; _Pragma("unroll") \
        for (int mi = 0; mi < 4; mi++) \
            af[mi] = *(const half8*)&As[wm + mi * 16 + lm][ks * 32 + quad * 8]; \
        _Pragma("unroll") \
        for (int ni = 0; ni < 4; ni++) \
            bf[ni] = *(const half8*)&Bs[wn + ni * 16 + lm][ks * 32 + quad * 8]; \
        _Pragma("unroll") \
        for (int mi = 0; mi < 4; mi++) _Pragma("unroll") \
            for (int ni = 0; ni < 4; ni++) \
                acc[mi][ni] = __builtin_amdgcn_mfma_f32_16x16x32_f16(af[mi], bf[ni], acc[mi][ni], 0, 0, 0); } }
#define PHASE(As_, Bs_, kk) { \
    STAGEA(As_); STAGEB(Bs_); \
    if ((kk) + 2 < PH) { LOADA(As_, (kk) + 2); LOADB(Bs_, (kk) + 2); } \
    BARRIER(); \
    MFMA_PHASE(); \
    BARRIER(); }

// ---- kernel 3a: GEMM + per-slice REPLICA plain stores ----
template<int NS>
__global__ __launch_bounds__(256) void k_gemm_rep(const u16* __restrict__ h16,
                                                  const signed char* __restrict__ wq,
                                                  const float* __restrict__ ws,
                                                  float* __restrict__ rep) {
    GEMM_BODY({
        float* rp = rep + (size_t)blockIdx.y * (B_ * FOUT);
        _Pragma("unroll")
        for (int mi = 0; mi < 4; mi++) _Pragma("unroll")
            for (int ni = 0; ni < 4; ni++) _Pragma("unroll")
                for (int r = 0; r < 4; r++) {
                    const int row = tm + wm + mi * 16 + quad * 4 + r;
                    const int col = tn + wn + ni * 16 + lm;
                    rp[row * FOUT + col] = acc[mi][ni][r];
                }
    })
}

// ---- kernel 3b: GEMM + atomic accumulate (fallback if ws too small) ----
template<int NS>
__global__ __launch_bounds__(256) void k_gemm_atm(const u16* __restrict__ h16,
                                                  const signed char* __restrict__ wq,
                                                  const float* __restrict__ ws,
                                                  float* __restrict__ accb) {
    GEMM_BODY({
        _Pragma("unroll")
        for (int mi = 0; mi < 4; mi++) _Pragma("unroll")
            for (int ni = 0; ni < 4; ni++) _Pragma("unroll")
                for (int r = 0; r < 4; r++) {
                    const int row = tm + wm + mi * 16 + quad * 4 + r;
                    const int col = tn + wn + ni * 16 + lm;
                    atomicAdd(accb + row * FOUT + col, acc[mi][ni][r]);
                }
    })
}
#undef LOADA
#undef LOADB
#undef STAGEA
#undef STAGEB
#undef BARRIER
#undef MFMA_PHASE
#undef PHASE
#undef GEMM_BODY

// ---- kernel 4a: reduce NS replicas + bias + relu ----
template<int NS>
__global__ void k_epi_rep(const float* __restrict__ rep, const float* __restrict__ db,
                          const float* __restrict__ ws, float* __restrict__ out) {
    const int idx = blockIdx.x * 256 + threadIdx.x;
    float s0 = 0.f, s1 = 0.f, s2 = 0.f, s3 = 0.f;
    #pragma unroll 4
    for (int r = 0; r < NS; r += 4) {
        s0 += rep[(size_t)(r + 0) * (B_ * FOUT) + idx];
        s1 += rep[(size_t)(r + 1) * (B_ * FOUT) + idx];
        s2 += rep[(size_t)(r + 2) * (B_ * FOUT) + idx];
        s3 += rep[(size_t)(r + 3) * (B_ * FOUT) + idx];
    }
    const float sum = (s0 + s1) + (s2 + s3);
    const int n = idx & 255;
    const float max_h = __uint_as_float(((const unsigned*)ws)[SC_F + 1]);
    const float p2 = fmaxf(max_h, 1e-8f) / 1023.0f;
    const float* wp = ws + WPART_F + (size_t)n * 4;
    const float am = fmaxf(fmaxf(fmaxf(wp[0], wp[1]), fmaxf(wp[2], wp[3])), 1e-8f);
    const float bsf = p2 * (am / 127.0f);
    const float bint = rintf(db[n] / bsf);
    out[idx] = fmaxf(0.f, (sum + bint) * bsf);
}

// ---- kernel 4b: fallback epilogue over atomic accb ----
__global__ void k_epi_atm(const float* __restrict__ accb, const float* __restrict__ db,
                          const float* __restrict__ ws, float* __restrict__ out) {
    const int idx = blockIdx.x * 256 + threadIdx.x;
    const int n = idx & 255;
    const float max_h = __uint_as_float(((const unsigned*)ws)[SC_F + 1]);
    const float p2 = fmaxf(max_h, 1e-8f) / 1023.0f;
    const float* wp = ws + WPART_F + (size_t)n * 4;
    const float am = fmaxf(fmaxf(fmaxf(wp[0], wp[1]), fmaxf(wp[2], wp[3])), 1e-8f);
    const float bsf = p2 * (am / 127.0f);
    const float bint = rintf(db[n] / bsf);
    out[idx] = fmaxf(0.f, (accb[idx] + bint) * bsf);
}

extern "C" void kernel_launch(void* const* d_in, const int* in_sizes, int n_in,
                              void* d_out, int out_size, void* d_ws, size_t ws_size,
                              hipStream_t stream) {
    (void)in_sizes; (void)n_in; (void)out_size;
    const float* x  = (const float*)d_in[0];
    const float* cw = (const float*)d_in[1];
    const float* cb = (const float*)d_in[2];
    const float* dw = (const float*)d_in[3];
    const float* db = (const float*)d_in[4];
    float* out = (float*)d_out;
    float* ws  = (float*)d_ws;
    u16* h16   = (u16*)((char*)d_ws + H16_BYTE);
    signed char* wq = (signed char*)d_ws + WQ_BYTE;
    float* rep  = (float*)((char*)d_ws + REP_BYTE);
    float* accb = ws + ACC_F;
    unsigned* maxh = (unsigned*)ws + SC_F + 1;

    const bool rep128 = (ws_size >= (size_t)WS_N128);
    const bool rep64  = (ws_size >= (size_t)WS_N64);

    // 4 enqueues: stats -> conv(+fused wq quant) -> gemm -> epilogue
    k_stats<<<rep64 ? 1537 : 1793, 256, 0, stream>>>(x, dw, cw, ws);
    k_conv<<<2048, 256, 0, stream>>>(x, dw, cb, ws, h16, wq, maxh);
    if (rep128) {
        k_gemm_rep<128><<<dim3(4, 128), 256, 0, stream>>>(h16, wq, ws, rep);
        k_epi_rep<128><<<256, 256, 0, stream>>>(rep, db, ws, out);
    } else if (rep64) {
        k_gemm_rep<64><<<dim3(4, 64), 256, 0, stream>>>(h16, wq, ws, rep);
        k_epi_rep<64><<<256, 256, 0, stream>>>(rep, db, ws, out);
    } else {
        k_gemm_atm<64><<<dim3(4, 64), 256, 0, stream>>>(h16, wq, ws, accb);
        k_epi_atm<<<256, 256, 0, stream>>>(accb, db, ws, out);
    }
}

// Round 17
// 179.599 us; speedup vs baseline: 1.1058x; 1.0437x over previous
//
#include <hip/hip_runtime.h>
#include <hip/hip_fp16.h>
#include <cstdint>

// Problem shape
#define B_   256
#define CIN  3
#define HW_  64
#define COUT 64
#define FIN  65536   // 64*32*32
#define FOUT 256

// Workspace layout (float indices)
#define ACC_F    0        // 65536: split-K accumulator (FALLBACK path only)
#define SC_F     65536    // 16: [1] = max_h bits (atomicMax; zeroed by k_stats)
#define XPART_F  65552    // 512: per-block partial absmax of x (plain writes)
#define WPART_F  66064    // 1024: per-(row,quarter) partial absmax of dense_w
#define CSF_F    67088    // 64: conv per-channel weight scale
#define CWINT_F  67152    // 1728: conv w_int (float-valued, s_load path in k_conv)
#define H16_BYTE (512*1024)                          // f16 h buffer, 33.5 MB
#define WQ_BYTE  (H16_BYTE + 256ll*FIN*2)            // int8 dense_w, 16.7 MB
#define REP_BYTE (WQ_BYTE + 256ll*FIN)               // 64 x 256KB f32 replicas, 16.8 MB
#define WS_NEED  (REP_BYTE + 64ll*B_*FOUT*4)         // ~67.6 MB (proven present, r14)

typedef _Float16 half8  __attribute__((ext_vector_type(8)));
typedef float    floatx4 __attribute__((ext_vector_type(4)));
typedef unsigned short u16;
typedef unsigned int uint_;

__device__ inline float blockMax(float v) {
    #pragma unroll
    for (int off = 32; off; off >>= 1) v = fmaxf(v, __shfl_down(v, off));
    __shared__ float sm[8];
    const int lane = threadIdx.x & 63, w = threadIdx.x >> 6;
    if (lane == 0) sm[w] = v;
    __syncthreads();
    float m = sm[0];
    const int nw = blockDim.x >> 6;
    for (int i = 1; i < nw; i++) m = fmaxf(m, sm[i]);
    return m;
}

// ---- kernel 1: input stats + conv weight quant (r14-identical) ----
__global__ __launch_bounds__(256) void k_stats(const float* __restrict__ x,
                                               const float* __restrict__ dw,
                                               const float* __restrict__ cw,
                                               float* __restrict__ ws) {
    const int b = blockIdx.x;
    const int t = threadIdx.x;
    if (b < 512) {
        const float4* x4 = (const float4*)x;
        float m = 0.f;
        for (int i = b * 256 + t; i < (B_ * CIN * HW_ * HW_) / 4; i += 512 * 256) {
            float4 v = x4[i];
            m = fmaxf(m, fmaxf(fmaxf(fabsf(v.x), fabsf(v.y)), fmaxf(fabsf(v.z), fabsf(v.w))));
        }
        float bm = blockMax(m);
        if (t == 0) ws[XPART_F + b] = bm;
    } else if (b < 1536) {
        const int b2 = b - 512;
        const int row = b2 >> 2, q = b2 & 3;
        const float4* r = (const float4*)(dw + (size_t)row * FIN) + q * 4096;
        float m = 0.f;
        for (int i = t; i < 4096; i += 256) {
            float4 v = r[i];
            m = fmaxf(m, fmaxf(fmaxf(fabsf(v.x), fabsf(v.y)), fmaxf(fabsf(v.z), fabsf(v.w))));
        }
        float bm = blockMax(m);
        if (t == 0) ws[WPART_F + b2] = bm;
    } else if (b == 1536) {
        if (t == 64) ((unsigned*)ws)[SC_F + 1] = 0u;   // zero max_h slot for k_conv's atomicMax
        if (t < 64) {
            const int o = t;
            float wv[27];
            float m = 0.f;
            #pragma unroll
            for (int i = 0; i < 27; i++) { wv[i] = cw[o * 27 + i]; m = fmaxf(m, fabsf(wv[i])); }
            const float sf = fmaxf(m, 1e-8f) / 127.0f;
            #pragma unroll
            for (int i = 0; i < 27; i++)
                ws[CWINT_F + o * 27 + i] = fminf(127.f, fmaxf(-127.f, rintf(wv[i] / sf)));
            ws[CSF_F + o] = sf;
        }
    } else {
        // fallback path only: zero the atomic accumulator
        ws[ACC_F + (b - 1537) * 256 + t] = 0.f;
    }
}

// ---- kernel 2: conv 3x3 s2 p1 + fused dense_w quant epilogue ----
// BYTE-IDENTICAL to r14 (best, 51.5us). r15 lesson: even REMOVING work from
// this kernel reshuffles codegen and costs 25% (65.5us). Do not touch.
__global__ __launch_bounds__(256) void k_conv(const float* __restrict__ x,
                                              const float* __restrict__ dw,
                                              const float* __restrict__ cb,
                                              const float* __restrict__ ws,
                                              u16* __restrict__ h16,
                                              signed char* __restrict__ wq,
                                              unsigned* __restrict__ maxh) {
    const int t = threadIdx.x;

    __shared__ float s_bsf[64], s_bint[64];
    __shared__ float xt[27 * 68];   // staged+requantized input, halo cols

    float pm = fmaxf(ws[XPART_F + t], ws[XPART_F + 256 + t]);
    pm = blockMax(pm);
    const float p_sf = fmaxf(pm, 1e-8f) / 32767.0f;
    const float inv_p = 1.0f / p_sf;
    if (t < 64) {
        const float bsf = p_sf * ws[CSF_F + t];
        s_bsf[t]  = bsf;
        s_bint[t] = rintf(cb[t] / bsf);
    }

    const int b   = blockIdx.x >> 3;
    const int oyt = (blockIdx.x & 7) * 4;
    const float* xb = x + (size_t)b * (CIN * HW_ * HW_);

    for (int i = t; i < 432; i += 256) {
        const int lrow = i >> 4, c4 = i & 15;
        const int ci = lrow / 9, lr = lrow - ci * 9;
        const int iy = 2 * oyt - 1 + lr;
        float4 v = make_float4(0.f, 0.f, 0.f, 0.f);
        if ((unsigned)iy < 64u) v = *(const float4*)(xb + (ci * HW_ + iy) * HW_ + c4 * 4);
        float* d = &xt[lrow * 68 + 1 + c4 * 4];
        d[0] = rintf(v.x * inv_p);   // |v|*inv_p <= 32767 by construction
        d[1] = rintf(v.y * inv_p);
        d[2] = rintf(v.z * inv_p);
        d[3] = rintf(v.w * inv_p);
    }
    if (t < 27) xt[t * 68] = 0.f;
    else if (t < 54) xt[(t - 27) * 68 + 65] = 0.f;
    __syncthreads();

    const int ox = t & 31;
    const int ch = __builtin_amdgcn_readfirstlane((t >> 6) & 1);
    const int dy = ((t >> 7) << 1) + ((t >> 5) & 1);
    const int oy = oyt + dy;

    // xs straight from xt, pinned to VGPRs
    float xs[27];
    #pragma unroll
    for (int ci = 0; ci < 3; ci++)
        #pragma unroll
        for (int ky = 0; ky < 3; ky++) {
            const float* rowp = &xt[(ci * 9 + 2 * dy + ky) * 68 + 2 * ox];
            float a0 = rowp[0], a1 = rowp[1], a2 = rowp[2];
            asm volatile("" : "+v"(a0), "+v"(a1), "+v"(a2));
            xs[ci * 9 + ky * 3 + 0] = a0;
            xs[ci * 9 + ky * 3 + 1] = a1;
            xs[ci * 9 + ky * 3 + 2] = a2;
        }

    const float* wr = ws + CWINT_F + ch * (32 * 27);  // uniform + const -> s_load
    float mx = 0.f;
    u16* outp = h16 + (size_t)b * FIN + (size_t)ch * 32 * 1024 + oy * 32 + ox;

#define EMIT(cc, aa) { const int co_ = ch * 32 + (cc); \
    float h_ = ((aa) + s_bint[co_]) * s_bsf[co_]; \
    h_ = fmaxf(h_, 0.f); mx = fmaxf(mx, h_); \
    outp[(size_t)(cc) * 1024] = __half_as_ushort(__float2half(h_)); }

    // two NAMED weight buffers: next channel's s_loads overlap current fmas
    float wA[27], wB[27];
    #pragma unroll
    for (int k = 0; k < 27; k++) wA[k] = wr[k];
    #pragma unroll
    for (int c = 0; c < 32; c += 2) {
        #pragma unroll
        for (int k = 0; k < 27; k++) wB[k] = wr[(c + 1) * 27 + k];
        float a = 0.f;
        #pragma unroll
        for (int k = 0; k < 27; k++) a = fmaf(xs[k], wA[k], a);
        EMIT(c, a);
        if (c + 2 < 32) {
            #pragma unroll
            for (int k = 0; k < 27; k++) wA[k] = wr[(c + 2) * 27 + k];
        }
        float a2 = 0.f;
        #pragma unroll
        for (int k = 0; k < 27; k++) a2 = fmaf(xs[k], wB[k], a2);
        EMIT(c + 1, a2);
    }
#undef EMIT
    float bm = blockMax(mx);
    if (t == 0) atomicMax(maxh, __float_as_uint(bm));

    // ---- fused dense_w quant epilogue: this block's 1/2048 share (8KB wq) ----
    {
        const int row = blockIdx.x >> 3;        // 0..255
        const int e8  = blockIdx.x & 7;         // eighth of the row
        const float* wp = ws + WPART_F + row * 4;
        const float am = fmaxf(fmaxf(wp[0], wp[1]), fmaxf(wp[2], wp[3]));
        const float inv = 127.0f / fmaxf(am, 1e-8f);
        const float4* r4 = (const float4*)(dw + (size_t)row * FIN) + e8 * 2048;
        uint_* wrow = (uint_*)(wq + (size_t)row * FIN) + e8 * 2048;
        for (int i = t; i < 2048; i += 256) {
            float4 v = r4[i];
            int q0 = __float2int_rn(v.x * inv);   // |v|*inv <= 127 by construction
            int q1 = __float2int_rn(v.y * inv);
            int q2 = __float2int_rn(v.z * inv);
            int q3 = __float2int_rn(v.w * inv);
            wrow[i] = (uint_)(q0 & 255) | ((uint_)(q1 & 255) << 8) |
                      ((uint_)(q2 & 255) << 16) | ((uint_)(q3 & 255) << 24);
        }
    }
}

// int8x8 -> half8 (values are small ints, exact in f16)
__device__ __forceinline__ half8 cvt_b8(uint_ lo, uint_ hi) {
    half8 h;
    h[0] = (_Float16)(float)(int)(signed char)(lo);
    h[1] = (_Float16)(float)(int)(signed char)(lo >> 8);
    h[2] = (_Float16)(float)(int)(signed char)(lo >> 16);
    h[3] = (_Float16)(float)(int)(signed char)(lo >> 24);
    h[4] = (_Float16)(float)(int)(signed char)(hi);
    h[5] = (_Float16)(float)(int)(signed char)(hi >> 8);
    h[6] = (_Float16)(float)(int)(signed char)(hi >> 16);
    h[7] = (_Float16)(float)(int)(signed char)(hi >> 24);
    return h;
}

// ---- gemm main-loop body (r14-identical: NS=64, 3-deep pipeline) ----
#define GEMM_BODY(EPILOGUE) \
    __shared__ __align__(16) _Float16 As[128][72]; \
    __shared__ __align__(16) _Float16 Bs[128][72]; \
    const int tid = threadIdx.x; \
    const int tm  = (blockIdx.x >> 1) * 128; \
    const int tn  = (blockIdx.x & 1) * 128; \
    const int k0  = blockIdx.y * 1024; \
    const float max_h  = __uint_as_float(((const unsigned*)ws)[SC_F + 1]); \
    const float p2     = fmaxf(max_h, 1e-8f) / 1023.0f; \
    const float inv_p2 = 1.0f / p2; \
    floatx4 acc[4][4]; \
    const floatx4 zz = {0.f, 0.f, 0.f, 0.f}; \
    _Pragma("unroll") \
    for (int i = 0; i < 4; i++) _Pragma("unroll") \
        for (int j = 0; j < 4; j++) acc[i][j] = zz; \
    const int wv = tid >> 6, lane = tid & 63; \
    const int wm = (wv >> 1) * 64, wn = (wv & 1) * 64; \
    const int lm = lane & 15, quad = lane >> 4; \
    const int arow = tid >> 3, acol = tid & 7; \
    const int brow = tid >> 1, bq   = (tid & 1) * 32; \
    const u16* abase = h16 + (size_t)(tm + arow) * FIN + k0 + acol * 8; \
    const signed char* bbase = wq + (size_t)(tn + brow) * FIN + k0 + bq; \
    half8 a0[4], a1[4], a2[4]; \
    uint4 b0[2], b1[2], b2[2]; \
    LOADA(a0, 0); LOADB(b0, 0); \
    LOADA(a1, 1); LOADB(b1, 1); \
    LOADA(a2, 2); LOADB(b2, 2); \
    PHASE(a0, b0, 0); \
    for (int it = 0; it < 5; ++it) { \
        PHASE(a1, b1, 3 * it + 1); \
        PHASE(a2, b2, 3 * it + 2); \
        PHASE(a0, b0, 3 * it + 3); \
    } \
    EPILOGUE

#define LOADA(dst, kk) { _Pragma("unroll") \
    for (int r = 0; r < 4; r++) \
        dst[r] = *(const half8*)(abase + (size_t)r * 32 * FIN + (kk) * 64); }
#define LOADB(dst, kk) { const uint4* p_ = (const uint4*)(bbase + (kk) * 64); \
    dst[0] = p_[0]; dst[1] = p_[1]; }
#define STAGEA(src) { _Pragma("unroll") \
    for (int r = 0; r < 4; r++) { half8 qv; _Pragma("unroll") \
        for (int j = 0; j < 8; j++) { float f_ = (float)src[r][j]; \
            qv[j] = (_Float16)fminf(1023.f, rintf(f_ * inv_p2)); } \
        *(half8*)&As[arow + r * 32][acol * 8] = qv; } }
#define STAGEB(src) { _Pragma("unroll") \
    for (int u = 0; u < 2; u++) { uint4 wd_ = src[u]; \
        *(half8*)&Bs[brow][bq + u * 16 + 0] = cvt_b8(wd_.x, wd_.y); \
        *(half8*)&Bs[brow][bq + u * 16 + 8] = cvt_b8(wd_.z, wd_.w); } }
#define BARRIER() do { asm volatile("s_waitcnt lgkmcnt(0)" ::: "memory"); \
    __builtin_amdgcn_s_barrier(); } while (0)
#define MFMA_PHASE() { _Pragma("unroll") \
    for (int ks = 0; ks < 2; ks++) { half8 af[4], bf[4]; _Pragma("unroll") \
        for (int mi = 0; mi < 4; mi++) \
            af[mi] = *(const half8*)&As[wm + mi * 16 + lm][ks * 32 + quad * 8]; \
        _Pragma("unroll") \
        for (int ni = 0; ni < 4; ni++) \
            bf[ni] = *(const half8*)&Bs[wn + ni * 16 + lm][ks * 32 + quad * 8]; \
        _Pragma("unroll") \
        for (int mi = 0; mi < 4; mi++) _Pragma("unroll") \
            for (int ni = 0; ni < 4; ni++) \
                acc[mi][ni] = __builtin_amdgcn_mfma_f32_16x16x32_f16(af[mi], bf[ni], acc[mi][ni], 0, 0, 0); } }
#define PHASE(As_, Bs_, kk) { \
    STAGEA(As_); STAGEB(Bs_); \
    if ((kk) + 3 < 16) { LOADA(As_, (kk) + 3); LOADB(Bs_, (kk) + 3); } \
    BARRIER(); \
    MFMA_PHASE(); \
    BARRIER(); }

// ---- kernel 3a: GEMM + per-slice REPLICA plain stores (r14-identical) ----
__global__ __launch_bounds__(256) void k_gemm_rep(const u16* __restrict__ h16,
                                                  const signed char* __restrict__ wq,
                                                  const float* __restrict__ ws,
                                                  float* __restrict__ rep) {
    GEMM_BODY({
        float* rp = rep + (size_t)blockIdx.y * (B_ * FOUT);
        _Pragma("unroll")
        for (int mi = 0; mi < 4; mi++) _Pragma("unroll")
            for (int ni = 0; ni < 4; ni++) _Pragma("unroll")
                for (int r = 0; r < 4; r++) {
                    const int row = tm + wm + mi * 16 + quad * 4 + r;
                    const int col = tn + wn + ni * 16 + lm;
                    rp[row * FOUT + col] = acc[mi][ni][r];
                }
    })
}

// ---- kernel 3b: GEMM + atomic accumulate (fallback if ws too small) ----
__global__ __launch_bounds__(256) void k_gemm_atm(const u16* __restrict__ h16,
                                                  const signed char* __restrict__ wq,
                                                  const float* __restrict__ ws,
                                                  float* __restrict__ accb) {
    GEMM_BODY({
        _Pragma("unroll")
        for (int mi = 0; mi < 4; mi++) _Pragma("unroll")
            for (int ni = 0; ni < 4; ni++) _Pragma("unroll")
                for (int r = 0; r < 4; r++) {
                    const int row = tm + wm + mi * 16 + quad * 4 + r;
                    const int col = tn + wn + ni * 16 + lm;
                    atomicAdd(accb + row * FOUT + col, acc[mi][ni][r]);
                }
    })
}
#undef LOADA
#undef LOADB
#undef STAGEA
#undef STAGEB
#undef BARRIER
#undef MFMA_PHASE
#undef PHASE
#undef GEMM_BODY

// ---- kernel 4a: reduce 64 replicas + bias + relu -- WIDE grid ----
// r17 change: 256 blocks = 1 block/CU was the thrice-measured latency-starve
// pattern (r0/r6/r8). 1024 blocks = 4/CU: each block owns 64 elements; its 4
// waves each sum a 16-replica quarter (lane-contiguous element reads =
// coalesced 256B/wave), combined via a 3x64 LDS slab.
__global__ __launch_bounds__(256) void k_epi_rep(const float* __restrict__ rep,
                                                 const float* __restrict__ db,
                                                 const float* __restrict__ ws,
                                                 float* __restrict__ out) {
    __shared__ float sm[3][64];
    const int t = threadIdx.x;
    const int l = t & 63, rq = t >> 6;          // lane-in-wave, replica quarter
    const int e = blockIdx.x * 64 + l;          // output element
    float s = 0.f;
    #pragma unroll
    for (int r = 0; r < 16; r++)
        s += rep[(size_t)(rq * 16 + r) * (B_ * FOUT) + e];
    if (rq) sm[rq - 1][l] = s;
    __syncthreads();
    if (rq == 0) {
        const float sum = s + sm[0][l] + sm[1][l] + sm[2][l];
        const int n = e & 255;
        const float max_h = __uint_as_float(((const unsigned*)ws)[SC_F + 1]);
        const float p2 = fmaxf(max_h, 1e-8f) / 1023.0f;
        const float* wp = ws + WPART_F + (size_t)n * 4;
        const float am = fmaxf(fmaxf(fmaxf(wp[0], wp[1]), fmaxf(wp[2], wp[3])), 1e-8f);
        const float bsf = p2 * (am / 127.0f);
        const float bint = rintf(db[n] / bsf);
        out[e] = fmaxf(0.f, (sum + bint) * bsf);
    }
}

// ---- kernel 4b: fallback epilogue over atomic accb ----
__global__ void k_epi_atm(const float* __restrict__ accb, const float* __restrict__ db,
                          const float* __restrict__ ws, float* __restrict__ out) {
    const int idx = blockIdx.x * 256 + threadIdx.x;
    const int n = idx & 255;
    const float max_h = __uint_as_float(((const unsigned*)ws)[SC_F + 1]);
    const float p2 = fmaxf(max_h, 1e-8f) / 1023.0f;
    const float* wp = ws + WPART_F + (size_t)n * 4;
    const float am = fmaxf(fmaxf(fmaxf(wp[0], wp[1]), fmaxf(wp[2], wp[3])), 1e-8f);
    const float bsf = p2 * (am / 127.0f);
    const float bint = rintf(db[n] / bsf);
    out[idx] = fmaxf(0.f, (accb[idx] + bint) * bsf);
}

extern "C" void kernel_launch(void* const* d_in, const int* in_sizes, int n_in,
                              void* d_out, int out_size, void* d_ws, size_t ws_size,
                              hipStream_t stream) {
    (void)in_sizes; (void)n_in; (void)out_size;
    const float* x  = (const float*)d_in[0];
    const float* cw = (const float*)d_in[1];
    const float* cb = (const float*)d_in[2];
    const float* dw = (const float*)d_in[3];
    const float* db = (const float*)d_in[4];
    float* out = (float*)d_out;
    float* ws  = (float*)d_ws;
    u16* h16   = (u16*)((char*)d_ws + H16_BYTE);
    signed char* wq = (signed char*)d_ws + WQ_BYTE;
    float* rep  = (float*)((char*)d_ws + REP_BYTE);
    float* accb = ws + ACC_F;
    unsigned* maxh = (unsigned*)ws + SC_F + 1;

    const bool use_rep = (ws_size >= (size_t)WS_NEED);

    // 4 enqueues: stats -> conv(+fused wq quant) -> gemm -> epilogue
    k_stats<<<use_rep ? 1537 : 1793, 256, 0, stream>>>(x, dw, cw, ws);
    k_conv<<<2048, 256, 0, stream>>>(x, dw, cb, ws, h16, wq, maxh);
    if (use_rep) {
        k_gemm_rep<<<dim3(4, 64), 256, 0, stream>>>(h16, wq, ws, rep);
        k_epi_rep<<<1024, 256, 0, stream>>>(rep, db, ws, out);
    } else {
        k_gemm_atm<<<dim3(4, 64), 256, 0, stream>>>(h16, wq, ws, accb);
        k_epi_atm<<<256, 256, 0, stream>>>(accb, db, ws, out);
    }
}